// Round 6
// baseline (159.837 us; speedup 1.0000x reference)
//
#include <hip/hip_runtime.h>
#include <stdint.h>

// DigitCaps with O=1: routing softmax over one out-capsule is identity, so
// the reference reduces to
//   s[b,v]  = sum_{i,d} W[i,v,d] * x[b,i,d]        (M=32, N=512, K=32768 GEMM)
//   out     = s * sqrt(sq)/(1+sq),  sq = sum_v s^2  (per-b squash)
// Both tuple outputs (t, outputs) are identical [32,1,512] tensors.
//
// R6: R3-R5 proved the compiler sinks VGPR-resident W prefetch regardless of
// source structure (VGPR_Count 20/72/32 vs data supposedly held). Switch W to
// the async DMA path it cannot touch: __builtin_amdgcn_global_load_lds
// (width 16) + double-buffered LDS, drained only at __syncthreads. x stays on
// the scalar pipe. 2 blocks/CU so co-resident waves hide each other's stalls.

#define NB 32
#define NI 4096
#define NV 512
#define ND 8
#define XSTRIDE (NI * ND)    // floats per batch row of x
#define IC 32                // i's per block chunk
#define NC (NI / IC)         // 128 chunks
#define NC8 (NC / 8)         // 16 second-stage groups
#define SC 4                 // i-rows per stage
#define NSC (IC / SC)        // 8 stages
#define ROWF (256 * ND)      // floats per staged row (v-half): 2048 (8 KB)
#define BUFF (SC * ROWF)     // floats per LDS buffer: 8192 (32 KB)

typedef __attribute__((address_space(1))) const uint32_t gq_t;
typedef __attribute__((address_space(3))) uint32_t       lq_t;

// ---------------------------------------------------------------------------
// Phase 1: partial[ic][b][v] = sum over i-chunk of W[i,v,:].x[b,i,:]
// Grid: 512 blocks = bg(2) x vh(2) x ic(128), XCD-swizzled (siblings sharing
// a W tile differ by 8 in blockIdx -> same XCD). 256 threads = 4 waves.
// Thread t -> v = vh*256 + t, accumulates b = bg*16 .. bg*16+15.
// W: async global->LDS DMA, double-buffered; stage sc+1 streams while
// computing stage sc. x: block-uniform scalar loads (s_load).
// ---------------------------------------------------------------------------
__global__ __launch_bounds__(256, 2) void caps_partial(
    const float* __restrict__ x, const float* __restrict__ W,
    float* __restrict__ partial)
{
    const int t    = threadIdx.x;
    const int lane = t & 63;
    const int wave = t >> 6;

    const int bx   = blockIdx.x;
    const int low3 = bx & 7;          // XCD id under round-robin dispatch
    const int bg   = (bx >> 3) & 1;   // bg siblings: ids differ by 8 -> same XCD
    const int c    = bx >> 4;
    const int tile = c * 8 + low3;    // 0..255
    const int vh   = tile & 1;
    const int ic   = tile >> 1;       // 0..127

    const int v0 = vh * 256;
    const int b0 = bg * 16;
    const int i0 = ic * IC;

    __shared__ float lds[2 * BUFF];   // 64 KB -> 2 blocks/CU

    float acc[16];
#pragma unroll
    for (int b = 0; b < 16; ++b) acc[b] = 0.0f;

    // Stage SC rows of W (this block's v-half) into buf. Wave w stages row w:
    // 8 KB contiguous = 8 x (64 lanes x 16 B) DMA calls. LDS layout == global
    // layout (contiguous, no padding) as global_load_lds requires.
    auto stage = [&](float* buf, int sc) {
        const float* g = W + ((size_t)(i0 + sc * SC + wave) * NV + v0) * ND + lane * 4;
        float* l = buf + wave * ROWF + lane * 4;
#pragma unroll
        for (int j = 0; j < 8; ++j) {
            __builtin_amdgcn_global_load_lds((gq_t*)(g + j * 256),
                                             (lq_t*)(l + j * 256), 16, 0, 0);
        }
    };

    auto compute = [&](const float* buf, int sc) {
        // hoist the stage's W rows for this thread's v into 32 VGPRs
        float4 w[2 * SC];
#pragma unroll
        for (int r = 0; r < SC; ++r) {
            const float4* p = (const float4*)(buf + r * ROWF + t * 8);
            w[2 * r]     = p[0];
            w[2 * r + 1] = p[1];
        }
        const float* xs = x + (size_t)b0 * XSTRIDE + (size_t)(i0 + sc * SC) * ND;
#pragma unroll
        for (int b = 0; b < 16; ++b) {
            const float* xq = xs + (size_t)b * XSTRIDE;  // uniform -> s_load
            float a = acc[b];
#pragma unroll
            for (int r = 0; r < SC; ++r) {
                a = fmaf(w[2 * r].x,     xq[r * 8 + 0], a);
                a = fmaf(w[2 * r].y,     xq[r * 8 + 1], a);
                a = fmaf(w[2 * r].z,     xq[r * 8 + 2], a);
                a = fmaf(w[2 * r].w,     xq[r * 8 + 3], a);
                a = fmaf(w[2 * r + 1].x, xq[r * 8 + 4], a);
                a = fmaf(w[2 * r + 1].y, xq[r * 8 + 5], a);
                a = fmaf(w[2 * r + 1].z, xq[r * 8 + 6], a);
                a = fmaf(w[2 * r + 1].w, xq[r * 8 + 7], a);
            }
            acc[b] = a;
        }
    };

    stage(lds, 0);
    for (int sc = 0; sc < NSC; ++sc) {
        __syncthreads();                 // vmcnt(0) drain: stage sc visible;
                                         // also: all waves done with buf sc^1
        if (sc + 1 < NSC)
            stage(lds + ((sc + 1) & 1) * BUFF, sc + 1);   // overlaps compute
        compute(lds + (sc & 1) * BUFF, sc);
    }

#pragma unroll
    for (int b = 0; b < 16; ++b)
        partial[((size_t)ic * NB + b0 + b) * NV + v0 + t] = acc[b];  // coalesced
}

// ---------------------------------------------------------------------------
// Phase 2a: tree reduce, 8 chunks -> 1.  Grid: NC8(16) x NB(32) = 512 blocks,
// 512 threads (one per v). 8 independent coalesced loads per thread (MLP).
// ---------------------------------------------------------------------------
__global__ __launch_bounds__(512) void caps_reduce8(
    const float* __restrict__ partial, float* __restrict__ partial2)
{
    const int v = threadIdx.x;
    const int b = blockIdx.x & 31;
    const int g = blockIdx.x >> 5;       // 0..NC8-1

    const float* p = partial + ((size_t)(g * 8) * NB + b) * NV + v;
    float s = 0.0f;
#pragma unroll
    for (int j = 0; j < 8; ++j)
        s += p[(size_t)j * NB * NV];

    partial2[((size_t)g * NB + b) * NV + v] = s;
}

// ---------------------------------------------------------------------------
// Phase 2b: final reduce over NC8 groups + squash + write both outputs.
// Grid: 32 blocks (one per b) x 512 threads (one per v).
// ---------------------------------------------------------------------------
__global__ __launch_bounds__(512) void caps_finish(
    const float* __restrict__ partial2, float* __restrict__ out)
{
    const int v = threadIdx.x;
    const int b = blockIdx.x;

    float s = 0.0f;
#pragma unroll
    for (int g = 0; g < NC8; ++g)        // 16 independent loads
        s += partial2[((size_t)g * NB + b) * NV + v];

    float sq = s * s;
#pragma unroll
    for (int off = 32; off > 0; off >>= 1)
        sq += __shfl_xor(sq, off, 64);

    __shared__ float red[8];
    if ((v & 63) == 0) red[v >> 6] = sq;
    __syncthreads();
    float tot = 0.0f;
#pragma unroll
    for (int wv = 0; wv < 8; ++wv) tot += red[wv];

    // squash factor: sq/((1+sq)*sqrt(sq)) == sqrt(sq)/(1+sq)
    const float factor = sqrtf(tot) / (1.0f + tot);
    const float r = s * factor;

    out[(size_t)b * NV + v]           = r;  // output 0: t       [B,1,V]
    out[NB * NV + (size_t)b * NV + v] = r;  // output 1: outputs [B,O,V]
}

extern "C" void kernel_launch(void* const* d_in, const int* in_sizes, int n_in,
                              void* d_out, int out_size, void* d_ws, size_t ws_size,
                              hipStream_t stream) {
    const float* x = (const float*)d_in[0];   // [32, 4096, 8]
    const float* W = (const float*)d_in[1];   // [1, 4096, 512, 8]
    float* out     = (float*)d_out;           // 2 x [32,1,512] concatenated

    float* partial  = (float*)d_ws;                       // 8 MB
    float* partial2 = partial + (size_t)NC * NB * NV;     // +1 MB (ws >= 16 MB)

    caps_partial<<<2 * 2 * NC, 256, 0, stream>>>(x, W, partial);
    caps_reduce8<<<NC8 * NB, 512, 0, stream>>>(partial, partial2);
    caps_finish<<<NB, 512, 0, stream>>>(partial2, out);
}

// Round 8
// 128.345 us; speedup vs baseline: 1.2454x; 1.2454x over previous
//
#include <hip/hip_runtime.h>
#include <stdint.h>

// DigitCaps with O=1: routing softmax over one out-capsule is identity, so
// the reference reduces to
//   s[b,v]  = sum_{i,d} W[i,v,d] * x[b,i,d]        (M=32, N=512, K=32768 GEMM)
//   out     = s * sqrt(sq)/(1+sq),  sq = sum_v s^2  (per-b squash)
// Both tuple outputs (t, outputs) are identical [32,1,512] tensors.
//
// R8 (= R7 retry, types fixed: clang's cvt_pkrtz / mfma f16 builtins use
// __fp16 ext-vectors, not _Float16): R3-R6 proved the fp32-VALU partition is
// issue/latency-floor-bound at ~51-78us regardless of W path. Switch compute
// class: MFMA f16 with 3-pass hi/lo split (x=xhi+xlo, w=whi+wlo; drop
// xlo*wlo ~2^-22 rel) -> fp32-class accuracy, ~13x less VALU, pure
// W-streaming kernel hidden by TLP.

#define NB 32
#define NI 4096
#define NV 512
#define ND 8
#define NK 32768            // K = NI*ND
#define KB 64               // k-blocks (partial slices)
#define KSB (NK / KB)       // 512 k per block
#define KSW (KSB / 4)       // 128 k per wave
#define KSTEPS (KSW / 16)   // 8 mfma k-steps per wave

typedef __fp16 f16x8 __attribute__((ext_vector_type(8)));
typedef __fp16 f16x2 __attribute__((ext_vector_type(2)));
typedef __fp16 f16x4 __attribute__((ext_vector_type(4)));
typedef float  f32x16 __attribute__((ext_vector_type(16)));

// ---------------------------------------------------------------------------
// Kernel 1: split x (fp32 [32][32768]) into f16 hi/lo planes [32][32768].
// hi = rtz(x); lo = rtz(x - hi). Grid: 1024 x 256, one float4 per thread.
// ---------------------------------------------------------------------------
__global__ __launch_bounds__(256) void x_prep(
    const float* __restrict__ x, __fp16* __restrict__ xhi,
    __fp16* __restrict__ xlo)
{
    const int idx = blockIdx.x * 256 + threadIdx.x;   // float4 index
    const float4 f = ((const float4*)x)[idx];

    f16x2 h0 = __builtin_amdgcn_cvt_pkrtz(f.x, f.y);
    f16x2 h1 = __builtin_amdgcn_cvt_pkrtz(f.z, f.w);
    f16x2 l0 = __builtin_amdgcn_cvt_pkrtz(f.x - (float)h0.x, f.y - (float)h0.y);
    f16x2 l1 = __builtin_amdgcn_cvt_pkrtz(f.z - (float)h1.x, f.w - (float)h1.y);

    f16x4 h = {h0.x, h0.y, h1.x, h1.y};
    f16x4 l = {l0.x, l0.y, l1.x, l1.y};
    ((f16x4*)xhi)[idx] = h;
    ((f16x4*)xlo)[idx] = l;
}

// ---------------------------------------------------------------------------
// Kernel 2: partial[kb][b][v] = sum over k-slice of x[b,k]*W[k,v] via MFMA.
// Grid: vg(16) x kb(64) = 1024 blocks, 256 threads = 4 waves.
// Wave tile: all 32 b x 32 v, K-subslice of 128 (wave w -> kb*512 + w*128).
// A-frag (x): lane L holds x[b = L&31][k + (L>>5)*8 + j] - direct f16x8 load.
// B-frag (W): lane L holds W[k + (L>>5)*8 + j][v0 + (L&31)] = fp32
//   W[i0+(L>>5)][v0+(L&31)][0..7] (32 B contiguous), cvt_pkrtz to hi/lo.
// 3 MFMAs per kstep: ahi*bhi + ahi*blo + alo*bhi into one f32x16 acc (AGPR).
// Epilogue: 4-wave LDS reduce -> one 32x32 tile per block.
// ---------------------------------------------------------------------------
__global__ __launch_bounds__(256, 4) void caps_mfma(
    const float* __restrict__ W, const __fp16* __restrict__ xhi,
    const __fp16* __restrict__ xlo, float* __restrict__ partial)
{
    const int t    = threadIdx.x;
    const int lane = t & 63;
    const int wave = t >> 6;
    const int half = lane >> 5;    // 0/1: which 8-k group
    const int ln32 = lane & 31;

    const int vg = blockIdx.x & 15;    // 16 v-groups of 32
    const int kb = blockIdx.x >> 4;    // 64 k-blocks
    const int v0 = vg * 32;
    const int k0 = kb * KSB + wave * KSW;
    const int i0 = (k0 >> 3) + half;   // starting W i-row for this lane

    f32x16 acc;
#pragma unroll
    for (int r = 0; r < 16; ++r) acc[r] = 0.0f;

    const __fp16* ah = xhi + (size_t)ln32 * NK + k0 + half * 8;
    const __fp16* al = xlo + (size_t)ln32 * NK + k0 + half * 8;
    const float4* wp = (const float4*)(W + ((size_t)i0 * NV + v0 + ln32) * ND);

#pragma unroll
    for (int s = 0; s < KSTEPS; ++s) {
        const f16x8 a_hi = *(const f16x8*)(ah + s * 16);
        const f16x8 a_lo = *(const f16x8*)(al + s * 16);
        const float4 w0 = wp[(size_t)s * 2 * NV * ND / 4];      // i += 2 per kstep
        const float4 w1 = wp[(size_t)s * 2 * NV * ND / 4 + 1];

        const f16x2 h01 = __builtin_amdgcn_cvt_pkrtz(w0.x, w0.y);
        const f16x2 h23 = __builtin_amdgcn_cvt_pkrtz(w0.z, w0.w);
        const f16x2 h45 = __builtin_amdgcn_cvt_pkrtz(w1.x, w1.y);
        const f16x2 h67 = __builtin_amdgcn_cvt_pkrtz(w1.z, w1.w);
        const f16x2 l01 = __builtin_amdgcn_cvt_pkrtz(w0.x - (float)h01.x,
                                                     w0.y - (float)h01.y);
        const f16x2 l23 = __builtin_amdgcn_cvt_pkrtz(w0.z - (float)h23.x,
                                                     w0.w - (float)h23.y);
        const f16x2 l45 = __builtin_amdgcn_cvt_pkrtz(w1.x - (float)h45.x,
                                                     w1.y - (float)h45.y);
        const f16x2 l67 = __builtin_amdgcn_cvt_pkrtz(w1.z - (float)h67.x,
                                                     w1.w - (float)h67.y);

        const f16x8 b_hi = {h01.x, h01.y, h23.x, h23.y, h45.x, h45.y, h67.x, h67.y};
        const f16x8 b_lo = {l01.x, l01.y, l23.x, l23.y, l45.x, l45.y, l67.x, l67.y};

        acc = __builtin_amdgcn_mfma_f32_32x32x16_f16(a_hi, b_hi, acc, 0, 0, 0);
        acc = __builtin_amdgcn_mfma_f32_32x32x16_f16(a_hi, b_lo, acc, 0, 0, 0);
        acc = __builtin_amdgcn_mfma_f32_32x32x16_f16(a_lo, b_hi, acc, 0, 0, 0);
    }

    // 4-wave k-reduce via LDS, then write the block's 32x32 tile.
    __shared__ float red[4 * 1024];   // 16 KB
#pragma unroll
    for (int r = 0; r < 16; ++r)
        red[wave * 1024 + r * 64 + lane] = acc[r];
    __syncthreads();

#pragma unroll
    for (int j = 0; j < 4; ++j) {
        const int s  = t + j * 256;
        const float val = red[s] + red[1024 + s] + red[2048 + s] + red[3072 + s];
        const int r   = s >> 6;
        const int ln  = s & 63;
        // C/D layout (m74/m101): col = lane&31 (v), row = (reg&3)+8*(reg>>2)+4*(lane>>5) (b)
        const int row = (r & 3) + 8 * (r >> 2) + 4 * (ln >> 5);
        const int col = ln & 31;
        partial[((size_t)kb * NB + row) * NV + v0 + col] = val;
    }
}

// ---------------------------------------------------------------------------
// Kernel 3: reduce KB slices + squash + write both outputs.
// Grid: 32 blocks (one per b) x 512 threads (one per v).
// ---------------------------------------------------------------------------
__global__ __launch_bounds__(512) void caps_finish(
    const float* __restrict__ partial, float* __restrict__ out)
{
    const int v = threadIdx.x;
    const int b = blockIdx.x;

    float s = 0.0f;
#pragma unroll
    for (int g = 0; g < KB; ++g)         // 64 independent coalesced loads
        s += partial[((size_t)g * NB + b) * NV + v];

    float sq = s * s;
#pragma unroll
    for (int off = 32; off > 0; off >>= 1)
        sq += __shfl_xor(sq, off, 64);

    __shared__ float red[8];
    if ((v & 63) == 0) red[v >> 6] = sq;
    __syncthreads();
    float tot = 0.0f;
#pragma unroll
    for (int wv = 0; wv < 8; ++wv) tot += red[wv];

    // squash factor: sq/((1+sq)*sqrt(sq)) == sqrt(sq)/(1+sq)
    const float factor = sqrtf(tot) / (1.0f + tot);
    const float r = s * factor;

    out[(size_t)b * NV + v]           = r;  // output 0: t       [B,1,V]
    out[NB * NV + (size_t)b * NV + v] = r;  // output 1: outputs [B,O,V]
}

extern "C" void kernel_launch(void* const* d_in, const int* in_sizes, int n_in,
                              void* d_out, int out_size, void* d_ws, size_t ws_size,
                              hipStream_t stream) {
    const float* x = (const float*)d_in[0];   // [32, 4096, 8]
    const float* W = (const float*)d_in[1];   // [1, 4096, 512, 8]
    float* out     = (float*)d_out;           // 2 x [32,1,512] concatenated

    __fp16* xhi    = (__fp16*)d_ws;                       // 2 MB
    __fp16* xlo    = xhi + (size_t)NB * NK;               // 2 MB
    float*  partial = (float*)(xlo + (size_t)NB * NK);    // 4 MB (ws >= 16 MB)

    x_prep<<<(NB * NK / 4) / 256, 256, 0, stream>>>(x, xhi, xlo);
    caps_mfma<<<16 * KB, 256, 0, stream>>>(W, xhi, xlo, partial);
    caps_finish<<<NB, 512, 0, stream>>>(partial, out);
}

// Round 9
// 127.117 us; speedup vs baseline: 1.2574x; 1.0097x over previous
//
#include <hip/hip_runtime.h>
#include <stdint.h>

// DigitCaps with O=1: routing softmax over one out-capsule is identity, so
// the reference reduces to
//   s[b,v]  = sum_{i,d} W[i,v,d] * x[b,i,d]        (M=32, N=512, K=32768 GEMM)
//   out     = s * sqrt(sq)/(1+sq),  sq = sum_v s^2  (per-b squash)
// Both tuple outputs (t, outputs) are identical [32,1,512] tensors.
//
// R9: R8 revealed (a) the ~80us "gap" = two ~41us harness 0xAA fills of the
// 256MB workspace (fixed floor), (b) caps_mfma ~38-40us because the fully
// unrolled body over-subscribed VGPRs (16 W-float4 + 64 VGPR a-frags) and the
// scheduler serialized load batches. Fixes: rolling loop (unroll 2, ~4 loads
// in flight), drop the W-lo MFMA (W f16-RTZ error ~2e-5 on output vs 3.46e-3
// threshold; x hi/lo split kept), and XCD swizzle so the 16 vg-siblings
// sharing an x-slice are co-XCD.

#define NB 32
#define NI 4096
#define NV 512
#define ND 8
#define NK 32768            // K = NI*ND
#define KB 64               // k-blocks (partial slices)
#define KSB (NK / KB)       // 512 k per block
#define KSW (KSB / 4)       // 128 k per wave
#define KSTEPS (KSW / 16)   // 8 mfma k-steps per wave

typedef __fp16 f16x8 __attribute__((ext_vector_type(8)));
typedef __fp16 f16x2 __attribute__((ext_vector_type(2)));
typedef __fp16 f16x4 __attribute__((ext_vector_type(4)));
typedef float  f32x16 __attribute__((ext_vector_type(16)));

// ---------------------------------------------------------------------------
// Kernel 1: split x (fp32 [32][32768]) into f16 hi/lo planes [32][32768].
// hi = rtz(x); lo = rtz(x - hi). Grid: 1024 x 256, one float4 per thread.
// ---------------------------------------------------------------------------
__global__ __launch_bounds__(256) void x_prep(
    const float* __restrict__ x, __fp16* __restrict__ xhi,
    __fp16* __restrict__ xlo)
{
    const int idx = blockIdx.x * 256 + threadIdx.x;   // float4 index
    const float4 f = ((const float4*)x)[idx];

    f16x2 h0 = __builtin_amdgcn_cvt_pkrtz(f.x, f.y);
    f16x2 h1 = __builtin_amdgcn_cvt_pkrtz(f.z, f.w);
    f16x2 l0 = __builtin_amdgcn_cvt_pkrtz(f.x - (float)h0.x, f.y - (float)h0.y);
    f16x2 l1 = __builtin_amdgcn_cvt_pkrtz(f.z - (float)h1.x, f.w - (float)h1.y);

    f16x4 h = {h0.x, h0.y, h1.x, h1.y};
    f16x4 l = {l0.x, l0.y, l1.x, l1.y};
    ((f16x4*)xhi)[idx] = h;
    ((f16x4*)xlo)[idx] = l;
}

// ---------------------------------------------------------------------------
// Kernel 2: partial[kb][b][v] = sum over k-slice of x[b,k]*W[k,v] via MFMA.
// Grid: kb(64) x vg(16) = 1024 blocks (kb fastest: the 16 vg-siblings that
// share an x-slice have ids differing by 64 -> same XCD). 256 thr = 4 waves.
// Wave tile: all 32 b x 32 v, K-subslice of 128 (wave w -> kb*512 + w*128).
// A-frag (x): lane L holds x[b = L&31][k + (L>>5)*8 + j] - direct f16x8 load.
// B-frag (W): lane L holds W[k + (L>>5)*8 + j][v0 + (L&31)] = fp32
//   W[i0+(L>>5)][v0+(L&31)][0..7] (32 B contiguous), cvt_pkrtz to f16.
// 2 MFMAs per kstep: ahi*w + alo*w into one f32x16 acc.
// Rolling loop (unroll 2): ~4 VMEM in flight, VGPR low, TLP hides latency.
// Epilogue: 4-wave LDS reduce -> one 32x32 tile per block.
// ---------------------------------------------------------------------------
__global__ __launch_bounds__(256) void caps_mfma(
    const float* __restrict__ W, const __fp16* __restrict__ xhi,
    const __fp16* __restrict__ xlo, float* __restrict__ partial)
{
    const int t    = threadIdx.x;
    const int lane = t & 63;
    const int wave = t >> 6;
    const int half = lane >> 5;    // 0/1: which 8-k group
    const int ln32 = lane & 31;

    const int kb = blockIdx.x & 63;    // fastest -> x-sharing siblings co-XCD
    const int vg = blockIdx.x >> 6;    // 16 v-groups of 32
    const int v0 = vg * 32;
    const int k0 = kb * KSB + wave * KSW;
    const int i0 = (k0 >> 3) + half;   // starting W i-row for this lane

    f32x16 acc;
#pragma unroll
    for (int r = 0; r < 16; ++r) acc[r] = 0.0f;

    const __fp16* ah = xhi + (size_t)ln32 * NK + k0 + half * 8;
    const __fp16* al = xlo + (size_t)ln32 * NK + k0 + half * 8;
    const float4* wp = (const float4*)(W + ((size_t)i0 * NV + v0 + ln32) * ND);

#pragma unroll 2
    for (int s = 0; s < KSTEPS; ++s) {
        const float4 w0 = wp[0];
        const float4 w1 = wp[1];
        wp += 2 * NV * ND / 4;                    // advance 2 i-rows
        const f16x8 a_hi = *(const f16x8*)ah;  ah += 16;
        const f16x8 a_lo = *(const f16x8*)al;  al += 16;

        const f16x2 h01 = __builtin_amdgcn_cvt_pkrtz(w0.x, w0.y);
        const f16x2 h23 = __builtin_amdgcn_cvt_pkrtz(w0.z, w0.w);
        const f16x2 h45 = __builtin_amdgcn_cvt_pkrtz(w1.x, w1.y);
        const f16x2 h67 = __builtin_amdgcn_cvt_pkrtz(w1.z, w1.w);
        const f16x8 b = {h01.x, h01.y, h23.x, h23.y, h45.x, h45.y, h67.x, h67.y};

        acc = __builtin_amdgcn_mfma_f32_32x32x16_f16(a_hi, b, acc, 0, 0, 0);
        acc = __builtin_amdgcn_mfma_f32_32x32x16_f16(a_lo, b, acc, 0, 0, 0);
    }

    // 4-wave k-reduce via LDS, then write the block's 32x32 tile.
    __shared__ float red[4 * 1024];   // 16 KB
#pragma unroll
    for (int r = 0; r < 16; ++r)
        red[wave * 1024 + r * 64 + lane] = acc[r];
    __syncthreads();

#pragma unroll
    for (int j = 0; j < 4; ++j) {
        const int s  = t + j * 256;
        const float val = red[s] + red[1024 + s] + red[2048 + s] + red[3072 + s];
        const int r   = s >> 6;
        const int ln  = s & 63;
        // C/D layout (m74/m101): col = lane&31 (v), row = (reg&3)+8*(reg>>2)+4*(lane>>5) (b)
        const int row = (r & 3) + 8 * (r >> 2) + 4 * (ln >> 5);
        const int col = ln & 31;
        partial[((size_t)kb * NB + row) * NV + v0 + col] = val;
    }
}

// ---------------------------------------------------------------------------
// Kernel 3: reduce KB slices + squash + write both outputs.
// Grid: 32 blocks (one per b) x 512 threads (one per v).
// ---------------------------------------------------------------------------
__global__ __launch_bounds__(512) void caps_finish(
    const float* __restrict__ partial, float* __restrict__ out)
{
    const int v = threadIdx.x;
    const int b = blockIdx.x;

    float s = 0.0f;
#pragma unroll
    for (int g = 0; g < KB; ++g)         // 64 independent coalesced loads
        s += partial[((size_t)g * NB + b) * NV + v];

    float sq = s * s;
#pragma unroll
    for (int off = 32; off > 0; off >>= 1)
        sq += __shfl_xor(sq, off, 64);

    __shared__ float red[8];
    if ((v & 63) == 0) red[v >> 6] = sq;
    __syncthreads();
    float tot = 0.0f;
#pragma unroll
    for (int wv = 0; wv < 8; ++wv) tot += red[wv];

    // squash factor: sq/((1+sq)*sqrt(sq)) == sqrt(sq)/(1+sq)
    const float factor = sqrtf(tot) / (1.0f + tot);
    const float r = s * factor;

    out[(size_t)b * NV + v]           = r;  // output 0: t       [B,1,V]
    out[NB * NV + (size_t)b * NV + v] = r;  // output 1: outputs [B,O,V]
}

extern "C" void kernel_launch(void* const* d_in, const int* in_sizes, int n_in,
                              void* d_out, int out_size, void* d_ws, size_t ws_size,
                              hipStream_t stream) {
    const float* x = (const float*)d_in[0];   // [32, 4096, 8]
    const float* W = (const float*)d_in[1];   // [1, 4096, 512, 8]
    float* out     = (float*)d_out;           // 2 x [32,1,512] concatenated

    __fp16* xhi    = (__fp16*)d_ws;                       // 2 MB
    __fp16* xlo    = xhi + (size_t)NB * NK;               // 2 MB
    float*  partial = (float*)(xlo + (size_t)NB * NK);    // 4 MB (ws >= 16 MB)

    x_prep<<<(NB * NK / 4) / 256, 256, 0, stream>>>(x, xhi, xlo);
    caps_mfma<<<KB * 16, 256, 0, stream>>>(W, xhi, xlo, partial);
    caps_finish<<<NB, 512, 0, stream>>>(partial, out);
}

// Round 10
// 118.094 us; speedup vs baseline: 1.3535x; 1.0764x over previous
//
#include <hip/hip_runtime.h>
#include <stdint.h>

// DigitCaps with O=1: routing softmax over one out-capsule is identity, so
// the reference reduces to
//   s[b,v]  = sum_{i,d} W[i,v,d] * x[b,i,d]        (M=32, N=512, K=32768 GEMM)
//   out     = s * sqrt(sq)/(1+sq),  sq = sum_v s^2  (per-b squash)
// Both tuple outputs (t, outputs) are identical [32,1,512] tensors.
//
// R10: R9's caps_mfma was ~3x over its W-stream floor because the A-fragment
// loads were 64-line gathers (lane L reads x[b=L&31][k], lanes 64 KB apart).
// Fix: x_prep stages x in MFMA-fragment order xt[(k>>3)*32 + b][k&7] so the
// a-load is 16 B/lane CONTIGUOUS (1 KB/wave). W stays fp32->f16 cvt in-loop;
// x keeps the hi/lo split (2 MFMAs) for fp32-class accuracy.
// Fixed harness floor: ~82us of 0xAA workspace fills + input restore.

#define NB 32
#define NI 4096
#define NV 512
#define ND 8
#define NK 32768            // K = NI*ND
#define KB 64               // k-blocks (partial slices)
#define KSB (NK / KB)       // 512 k per block
#define KSW (KSB / 4)       // 128 k per wave
#define KSTEPS (KSW / 16)   // 8 mfma k-steps per wave

typedef __fp16 f16x8 __attribute__((ext_vector_type(8)));
typedef __fp16 f16x2 __attribute__((ext_vector_type(2)));
typedef float  f32x16 __attribute__((ext_vector_type(16)));

// ---------------------------------------------------------------------------
// Kernel 1: split x (fp32 [32][32768]) into f16 hi/lo planes in FRAGMENT
// order: xt[(g*32 + b)*8 + j] where g=k>>3, j=k&7. hi = rtz(x); lo = x - hi.
// Thread tid -> (b = tid&31, g = tid>>5): reads 32 B of x[b], writes one
// f16x8 per plane; writes are fully coalesced (consecutive tid -> contiguous).
// ---------------------------------------------------------------------------
__global__ __launch_bounds__(256) void x_prep(
    const float* __restrict__ x, __fp16* __restrict__ xh,
    __fp16* __restrict__ xl)
{
    const int tid = blockIdx.x * 256 + threadIdx.x;   // 131072 total
    const int b = tid & 31;
    const int g = tid >> 5;

    const float4* xp = (const float4*)(x + (size_t)b * NK + (size_t)g * 8);
    const float4 f0 = xp[0];
    const float4 f1 = xp[1];

    const f16x2 h0 = __builtin_amdgcn_cvt_pkrtz(f0.x, f0.y);
    const f16x2 h1 = __builtin_amdgcn_cvt_pkrtz(f0.z, f0.w);
    const f16x2 h2 = __builtin_amdgcn_cvt_pkrtz(f1.x, f1.y);
    const f16x2 h3 = __builtin_amdgcn_cvt_pkrtz(f1.z, f1.w);
    const f16x2 l0 = __builtin_amdgcn_cvt_pkrtz(f0.x - (float)h0.x, f0.y - (float)h0.y);
    const f16x2 l1 = __builtin_amdgcn_cvt_pkrtz(f0.z - (float)h1.x, f0.w - (float)h1.y);
    const f16x2 l2 = __builtin_amdgcn_cvt_pkrtz(f1.x - (float)h2.x, f1.y - (float)h2.y);
    const f16x2 l3 = __builtin_amdgcn_cvt_pkrtz(f1.z - (float)h3.x, f1.w - (float)h3.y);

    const f16x8 h = {h0.x, h0.y, h1.x, h1.y, h2.x, h2.y, h3.x, h3.y};
    const f16x8 l = {l0.x, l0.y, l1.x, l1.y, l2.x, l2.y, l3.x, l3.y};
    ((f16x8*)xh)[tid] = h;
    ((f16x8*)xl)[tid] = l;
}

// ---------------------------------------------------------------------------
// Kernel 2: partial[kb][b][v] = sum over k-slice of x[b,k]*W[k,v] via MFMA.
// Grid: kb(64) x vg(16) = 1024 blocks (kb fastest: the 16 vg-siblings that
// share an x-slice have ids differing by 64 -> same XCD). 256 thr = 4 waves.
// Wave tile: all 32 b x 32 v, K-subslice of 128 (wave w -> kb*512 + w*128).
// A-frag (x): lane L holds x[b=L&31][k + (L>>5)*8 + j]; from xt this is a
//   CONTIGUOUS f16x8 at ((g+half)*32 + ln32)*8 -> 1 KB/wave coalesced.
// B-frag (W): lane L holds W[i=k>>3 rows][v0+(L&31)][0..7]: 32 B contiguous
//   fp32, cvt_pkrtz to f16 in-loop.
// 2 MFMAs per kstep (x hi + x lo). Rolling loop, unroll 2.
// Epilogue: 4-wave LDS k-reduce -> one 32x32 tile per block.
// ---------------------------------------------------------------------------
__global__ __launch_bounds__(256) void caps_mfma(
    const float* __restrict__ W, const __fp16* __restrict__ xh,
    const __fp16* __restrict__ xl, float* __restrict__ partial)
{
    const int t    = threadIdx.x;
    const int lane = t & 63;
    const int wave = t >> 6;
    const int half = lane >> 5;    // 0/1: which 8-k group of the 16-k step
    const int ln32 = lane & 31;

    const int kb = blockIdx.x & 63;    // fastest -> x-sharing siblings co-XCD
    const int vg = blockIdx.x >> 6;    // 16 v-groups of 32
    const int v0 = vg * 32;
    const int k0 = kb * KSB + wave * KSW;
    const int g0 = (k0 >> 3) + half;   // starting k-group for this lane

    f32x16 acc;
#pragma unroll
    for (int r = 0; r < 16; ++r) acc[r] = 0.0f;

    const __fp16* ah = xh + ((size_t)g0 * 32 + ln32) * 8;
    const __fp16* al = xl + ((size_t)g0 * 32 + ln32) * 8;
    const float4* wp = (const float4*)(W + ((size_t)g0 * NV + v0 + ln32) * ND);

#pragma unroll 2
    for (int s = 0; s < KSTEPS; ++s) {
        const float4 w0 = wp[0];
        const float4 w1 = wp[1];
        wp += 2 * NV * ND / 4;                       // advance 2 i-rows
        const f16x8 a_hi = *(const f16x8*)ah;  ah += 2 * 32 * 8;
        const f16x8 a_lo = *(const f16x8*)al;  al += 2 * 32 * 8;

        const f16x2 h01 = __builtin_amdgcn_cvt_pkrtz(w0.x, w0.y);
        const f16x2 h23 = __builtin_amdgcn_cvt_pkrtz(w0.z, w0.w);
        const f16x2 h45 = __builtin_amdgcn_cvt_pkrtz(w1.x, w1.y);
        const f16x2 h67 = __builtin_amdgcn_cvt_pkrtz(w1.z, w1.w);
        const f16x8 b = {h01.x, h01.y, h23.x, h23.y, h45.x, h45.y, h67.x, h67.y};

        acc = __builtin_amdgcn_mfma_f32_32x32x16_f16(a_hi, b, acc, 0, 0, 0);
        acc = __builtin_amdgcn_mfma_f32_32x32x16_f16(a_lo, b, acc, 0, 0, 0);
    }

    // 4-wave k-reduce via LDS, then write the block's 32x32 tile.
    __shared__ float red[4 * 1024];   // 16 KB
#pragma unroll
    for (int r = 0; r < 16; ++r)
        red[wave * 1024 + r * 64 + lane] = acc[r];
    __syncthreads();

#pragma unroll
    for (int j = 0; j < 4; ++j) {
        const int s  = t + j * 256;
        const float val = red[s] + red[1024 + s] + red[2048 + s] + red[3072 + s];
        const int r   = s >> 6;
        const int ln  = s & 63;
        // C/D layout (m74/m101): col = lane&31 (v), row = (reg&3)+8*(reg>>2)+4*(lane>>5) (b)
        const int row = (r & 3) + 8 * (r >> 2) + 4 * (ln >> 5);
        const int col = ln & 31;
        partial[((size_t)kb * NB + row) * NV + v0 + col] = val;
    }
}

// ---------------------------------------------------------------------------
// Kernel 3: reduce KB slices + squash + write both outputs.
// Grid: 32 blocks (one per b) x 512 threads (one per v).
// ---------------------------------------------------------------------------
__global__ __launch_bounds__(512) void caps_finish(
    const float* __restrict__ partial, float* __restrict__ out)
{
    const int v = threadIdx.x;
    const int b = blockIdx.x;

    float s = 0.0f;
#pragma unroll
    for (int g = 0; g < KB; ++g)         // 64 independent coalesced loads
        s += partial[((size_t)g * NB + b) * NV + v];

    float sq = s * s;
#pragma unroll
    for (int off = 32; off > 0; off >>= 1)
        sq += __shfl_xor(sq, off, 64);

    __shared__ float red[8];
    if ((v & 63) == 0) red[v >> 6] = sq;
    __syncthreads();
    float tot = 0.0f;
#pragma unroll
    for (int wv = 0; wv < 8; ++wv) tot += red[wv];

    // squash factor: sq/((1+sq)*sqrt(sq)) == sqrt(sq)/(1+sq)
    const float factor = sqrtf(tot) / (1.0f + tot);
    const float r = s * factor;

    out[(size_t)b * NV + v]           = r;  // output 0: t       [B,1,V]
    out[NB * NV + (size_t)b * NV + v] = r;  // output 1: outputs [B,O,V]
}

extern "C" void kernel_launch(void* const* d_in, const int* in_sizes, int n_in,
                              void* d_out, int out_size, void* d_ws, size_t ws_size,
                              hipStream_t stream) {
    const float* x = (const float*)d_in[0];   // [32, 4096, 8]
    const float* W = (const float*)d_in[1];   // [1, 4096, 512, 8]
    float* out     = (float*)d_out;           // 2 x [32,1,512] concatenated

    __fp16* xh     = (__fp16*)d_ws;                       // 2 MB
    __fp16* xl     = xh + (size_t)NB * NK;                // 2 MB
    float*  partial = (float*)(xl + (size_t)NB * NK);     // 4 MB (ws >= 16 MB)

    x_prep<<<(NB * NK / 8) / 256, 256, 0, stream>>>(x, xh, xl);
    caps_mfma<<<KB * 16, 256, 0, stream>>>(W, xh, xl, partial);
    caps_finish<<<NB, 512, 0, stream>>>(partial, out);
}

// Round 11
// 110.148 us; speedup vs baseline: 1.4511x; 1.0721x over previous
//
#include <hip/hip_runtime.h>
#include <stdint.h>

// DigitCaps with O=1: routing softmax over one out-capsule is identity, so
// the reference reduces to
//   s[b,v]  = sum_{i,d} W[i,v,d] * x[b,i,d]        (M=32, N=512, K=32768 GEMM)
//   out     = s * sqrt(sq)/(1+sq),  sq = sum_v s^2  (per-b squash)
// Both tuple outputs (t, outputs) are identical [32,1,512] tensors.
//
// R11: budget is now clean: ~82us = two harness 0xAA fills of the 256MB ws
// (fixed floor); controllable kernels ~36us, of which caps_mfma ~25us vs a
// 10.8us stream floor. Diagnosis: concurrency starvation - waves stall at
// s_waitcnt for ~900cyc with only 4 waves/SIMD of TLP. Fix: KB 64->128
// (2048 blocks, KSTEPS=4) -> ~7-8 waves/SIMD, ~2x HBM requests in flight.
// Everything else unchanged from R10 (fragment-order x planes, 2 MFMA/kstep,
// in-loop W cvt, XCD swizzle).

#define NB 32
#define NI 4096
#define NV 512
#define ND 8
#define NK 32768            // K = NI*ND
#define KB 128              // k-blocks (partial slices)
#define KSB (NK / KB)       // 256 k per block
#define KSW (KSB / 4)       // 64 k per wave
#define KSTEPS (KSW / 16)   // 4 mfma k-steps per wave

typedef __fp16 f16x8 __attribute__((ext_vector_type(8)));
typedef __fp16 f16x2 __attribute__((ext_vector_type(2)));
typedef float  f32x16 __attribute__((ext_vector_type(16)));

// ---------------------------------------------------------------------------
// Kernel 1: split x (fp32 [32][32768]) into f16 hi/lo planes in FRAGMENT
// order: xt[(g*32 + b)*8 + j] where g=k>>3, j=k&7. hi = rtz(x); lo = x - hi.
// Thread tid -> (b = tid&31, g = tid>>5); reads are 64B-segment-friendly
// (g,g+1 of same b pair up), writes fully coalesced.
// ---------------------------------------------------------------------------
__global__ __launch_bounds__(256) void x_prep(
    const float* __restrict__ x, __fp16* __restrict__ xh,
    __fp16* __restrict__ xl)
{
    const int tid = blockIdx.x * 256 + threadIdx.x;   // 131072 total
    const int b = tid & 31;
    const int g = tid >> 5;

    const float4* xp = (const float4*)(x + (size_t)b * NK + (size_t)g * 8);
    const float4 f0 = xp[0];
    const float4 f1 = xp[1];

    const f16x2 h0 = __builtin_amdgcn_cvt_pkrtz(f0.x, f0.y);
    const f16x2 h1 = __builtin_amdgcn_cvt_pkrtz(f0.z, f0.w);
    const f16x2 h2 = __builtin_amdgcn_cvt_pkrtz(f1.x, f1.y);
    const f16x2 h3 = __builtin_amdgcn_cvt_pkrtz(f1.z, f1.w);
    const f16x2 l0 = __builtin_amdgcn_cvt_pkrtz(f0.x - (float)h0.x, f0.y - (float)h0.y);
    const f16x2 l1 = __builtin_amdgcn_cvt_pkrtz(f0.z - (float)h1.x, f0.w - (float)h1.y);
    const f16x2 l2 = __builtin_amdgcn_cvt_pkrtz(f1.x - (float)h2.x, f1.y - (float)h2.y);
    const f16x2 l3 = __builtin_amdgcn_cvt_pkrtz(f1.z - (float)h3.x, f1.w - (float)h3.y);

    const f16x8 h = {h0.x, h0.y, h1.x, h1.y, h2.x, h2.y, h3.x, h3.y};
    const f16x8 l = {l0.x, l0.y, l1.x, l1.y, l2.x, l2.y, l3.x, l3.y};
    ((f16x8*)xh)[tid] = h;
    ((f16x8*)xl)[tid] = l;
}

// ---------------------------------------------------------------------------
// Kernel 2: partial[kb][b][v] = sum over k-slice of x[b,k]*W[k,v] via MFMA.
// Grid: kb(128) x vg(16) = 2048 blocks (kb fastest: the 16 vg-siblings that
// share an x-slice have ids differing by 128 -> same XCD). 256 thr = 4 waves.
// Wave tile: all 32 b x 32 v, K-subslice of 64 (wave w -> kb*256 + w*64).
// A-frag (x): contiguous f16x8 per lane from the fragment-ordered planes.
// B-frag (W): lane L holds W[rows g0,g0+1,...][v0+(L&31)][0..7]: 32 B
//   contiguous fp32, cvt_pkrtz to f16 in-loop.
// 2 MFMAs per kstep (x hi + x lo). Rolling loop, unroll 2.
// Epilogue: 4-wave LDS k-reduce -> one 32x32 tile per block.
// ---------------------------------------------------------------------------
__global__ __launch_bounds__(256) void caps_mfma(
    const float* __restrict__ W, const __fp16* __restrict__ xh,
    const __fp16* __restrict__ xl, float* __restrict__ partial)
{
    const int t    = threadIdx.x;
    const int lane = t & 63;
    const int wave = t >> 6;
    const int half = lane >> 5;    // 0/1: which 8-k group of the 16-k step
    const int ln32 = lane & 31;

    const int kb = blockIdx.x & (KB - 1);   // fastest -> x-sharing siblings co-XCD
    const int vg = blockIdx.x >> 7;         // 16 v-groups of 32
    const int v0 = vg * 32;
    const int k0 = kb * KSB + wave * KSW;
    const int g0 = (k0 >> 3) + half;        // starting k-group for this lane

    f32x16 acc;
#pragma unroll
    for (int r = 0; r < 16; ++r) acc[r] = 0.0f;

    const __fp16* ah = xh + ((size_t)g0 * 32 + ln32) * 8;
    const __fp16* al = xl + ((size_t)g0 * 32 + ln32) * 8;
    const float4* wp = (const float4*)(W + ((size_t)g0 * NV + v0 + ln32) * ND);

#pragma unroll 2
    for (int s = 0; s < KSTEPS; ++s) {
        const float4 w0 = wp[0];
        const float4 w1 = wp[1];
        wp += 2 * NV * ND / 4;                       // advance 2 i-rows
        const f16x8 a_hi = *(const f16x8*)ah;  ah += 2 * 32 * 8;
        const f16x8 a_lo = *(const f16x8*)al;  al += 2 * 32 * 8;

        const f16x2 h01 = __builtin_amdgcn_cvt_pkrtz(w0.x, w0.y);
        const f16x2 h23 = __builtin_amdgcn_cvt_pkrtz(w0.z, w0.w);
        const f16x2 h45 = __builtin_amdgcn_cvt_pkrtz(w1.x, w1.y);
        const f16x2 h67 = __builtin_amdgcn_cvt_pkrtz(w1.z, w1.w);
        const f16x8 b = {h01.x, h01.y, h23.x, h23.y, h45.x, h45.y, h67.x, h67.y};

        acc = __builtin_amdgcn_mfma_f32_32x32x16_f16(a_hi, b, acc, 0, 0, 0);
        acc = __builtin_amdgcn_mfma_f32_32x32x16_f16(a_lo, b, acc, 0, 0, 0);
    }

    // 4-wave k-reduce via LDS, then write the block's 32x32 tile.
    __shared__ float red[4 * 1024];   // 16 KB
#pragma unroll
    for (int r = 0; r < 16; ++r)
        red[wave * 1024 + r * 64 + lane] = acc[r];
    __syncthreads();

#pragma unroll
    for (int j = 0; j < 4; ++j) {
        const int s  = t + j * 256;
        const float val = red[s] + red[1024 + s] + red[2048 + s] + red[3072 + s];
        const int r   = s >> 6;
        const int ln  = s & 63;
        // C/D layout (m74/m101): col = lane&31 (v), row = (reg&3)+8*(reg>>2)+4*(lane>>5) (b)
        const int row = (r & 3) + 8 * (r >> 2) + 4 * (ln >> 5);
        const int col = ln & 31;
        partial[((size_t)kb * NB + row) * NV + v0 + col] = val;
    }
}

// ---------------------------------------------------------------------------
// Kernel 3: reduce KB slices + squash + write both outputs.
// Grid: 32 blocks (one per b) x 512 threads (one per v).
// ---------------------------------------------------------------------------
__global__ __launch_bounds__(512) void caps_finish(
    const float* __restrict__ partial, float* __restrict__ out)
{
    const int v = threadIdx.x;
    const int b = blockIdx.x;

    float s = 0.0f;
#pragma unroll 16
    for (int g = 0; g < KB; ++g)         // independent coalesced loads
        s += partial[((size_t)g * NB + b) * NV + v];

    float sq = s * s;
#pragma unroll
    for (int off = 32; off > 0; off >>= 1)
        sq += __shfl_xor(sq, off, 64);

    __shared__ float red[8];
    if ((v & 63) == 0) red[v >> 6] = sq;
    __syncthreads();
    float tot = 0.0f;
#pragma unroll
    for (int wv = 0; wv < 8; ++wv) tot += red[wv];

    // squash factor: sq/((1+sq)*sqrt(sq)) == sqrt(sq)/(1+sq)
    const float factor = sqrtf(tot) / (1.0f + tot);
    const float r = s * factor;

    out[(size_t)b * NV + v]           = r;  // output 0: t       [B,1,V]
    out[NB * NV + (size_t)b * NV + v] = r;  // output 1: outputs [B,O,V]
}

extern "C" void kernel_launch(void* const* d_in, const int* in_sizes, int n_in,
                              void* d_out, int out_size, void* d_ws, size_t ws_size,
                              hipStream_t stream) {
    const float* x = (const float*)d_in[0];   // [32, 4096, 8]
    const float* W = (const float*)d_in[1];   // [1, 4096, 512, 8]
    float* out     = (float*)d_out;           // 2 x [32,1,512] concatenated

    __fp16* xh     = (__fp16*)d_ws;                       // 2 MB
    __fp16* xl     = xh + (size_t)NB * NK;                // 2 MB
    float*  partial = (float*)(xl + (size_t)NB * NK);     // 8 MB (ws >= 16 MB)

    x_prep<<<(NB * NK / 8) / 256, 256, 0, stream>>>(x, xh, xl);
    caps_mfma<<<KB * 16, 256, 0, stream>>>(W, xh, xl, partial);
    caps_finish<<<NB, 512, 0, stream>>>(partial, out);
}

// Round 12
// 108.218 us; speedup vs baseline: 1.4770x; 1.0178x over previous
//
#include <hip/hip_runtime.h>
#include <stdint.h>

// DigitCaps with O=1: routing softmax over one out-capsule is identity, so
// the reference reduces to
//   s[b,v]  = sum_{i,d} W[i,v,d] * x[b,i,d]        (M=32, N=512, K=32768 GEMM)
//   out     = s * sqrt(sq)/(1+sq),  sq = sum_v s^2  (per-b squash)
// Both tuple outputs (t, outputs) are identical [32,1,512] tensors.
//
// R12: R11 saturated caps_mfma's TLP (7 waves/SIMD resident; KB=128 already
// supplies 8 waves/SIMD of work). The remaining fat is the reduce chain:
// caps_finish read 8 MB with only 32 blocks (~8-10us). Fixes: partial stored
// as f16 (error contribution ~2e-5 on output scale vs 2.5e-3 margin), and a
// two-stage tree reduce (512-block stage + 1 MB final stage).
// Fixed harness floor: ~83us of 0xAA workspace fills.

#define NB 32
#define NI 4096
#define NV 512
#define ND 8
#define NK 32768            // K = NI*ND
#define KB 128              // k-blocks (partial slices)
#define KSB (NK / KB)       // 256 k per block
#define KSW (KSB / 4)       // 64 k per wave
#define KSTEPS (KSW / 16)   // 4 mfma k-steps per wave
#define NG (KB / 8)         // 16 second-stage groups

typedef __fp16 f16x8 __attribute__((ext_vector_type(8)));
typedef __fp16 f16x2 __attribute__((ext_vector_type(2)));
typedef float  f32x16 __attribute__((ext_vector_type(16)));

// ---------------------------------------------------------------------------
// Kernel 1: split x (fp32 [32][32768]) into f16 hi/lo planes in FRAGMENT
// order: xt[(g*32 + b)*8 + j] where g=k>>3, j=k&7. hi = rtz(x); lo = x - hi.
// ---------------------------------------------------------------------------
__global__ __launch_bounds__(256) void x_prep(
    const float* __restrict__ x, __fp16* __restrict__ xh,
    __fp16* __restrict__ xl)
{
    const int tid = blockIdx.x * 256 + threadIdx.x;   // 131072 total
    const int b = tid & 31;
    const int g = tid >> 5;

    const float4* xp = (const float4*)(x + (size_t)b * NK + (size_t)g * 8);
    const float4 f0 = xp[0];
    const float4 f1 = xp[1];

    const f16x2 h0 = __builtin_amdgcn_cvt_pkrtz(f0.x, f0.y);
    const f16x2 h1 = __builtin_amdgcn_cvt_pkrtz(f0.z, f0.w);
    const f16x2 h2 = __builtin_amdgcn_cvt_pkrtz(f1.x, f1.y);
    const f16x2 h3 = __builtin_amdgcn_cvt_pkrtz(f1.z, f1.w);
    const f16x2 l0 = __builtin_amdgcn_cvt_pkrtz(f0.x - (float)h0.x, f0.y - (float)h0.y);
    const f16x2 l1 = __builtin_amdgcn_cvt_pkrtz(f0.z - (float)h1.x, f0.w - (float)h1.y);
    const f16x2 l2 = __builtin_amdgcn_cvt_pkrtz(f1.x - (float)h2.x, f1.y - (float)h2.y);
    const f16x2 l3 = __builtin_amdgcn_cvt_pkrtz(f1.z - (float)h3.x, f1.w - (float)h3.y);

    const f16x8 h = {h0.x, h0.y, h1.x, h1.y, h2.x, h2.y, h3.x, h3.y};
    const f16x8 l = {l0.x, l0.y, l1.x, l1.y, l2.x, l2.y, l3.x, l3.y};
    ((f16x8*)xh)[tid] = h;
    ((f16x8*)xl)[tid] = l;
}

// ---------------------------------------------------------------------------
// Kernel 2: partial_h[kb][b][v] (f16) = sum over k-slice of x[b,k]*W[k,v].
// Grid: kb(128) x vg(16) = 2048 blocks (kb fastest: x-sharing vg-siblings
// co-XCD). 256 thr = 4 waves; wave tile 32b x 32v, 64 k per wave.
// A-frag: contiguous f16x8 per lane (fragment-ordered planes).
// B-frag: 32 B contiguous fp32 W, cvt_pkrtz in-loop. 2 MFMAs/kstep (x hi+lo).
// Epilogue: 4-wave LDS k-reduce -> f16 32x32 tile.
// ---------------------------------------------------------------------------
__global__ __launch_bounds__(256) void caps_mfma(
    const float* __restrict__ W, const __fp16* __restrict__ xh,
    const __fp16* __restrict__ xl, __fp16* __restrict__ partial_h)
{
    const int t    = threadIdx.x;
    const int lane = t & 63;
    const int wave = t >> 6;
    const int half = lane >> 5;
    const int ln32 = lane & 31;

    const int kb = blockIdx.x & (KB - 1);
    const int vg = blockIdx.x >> 7;
    const int v0 = vg * 32;
    const int k0 = kb * KSB + wave * KSW;
    const int g0 = (k0 >> 3) + half;

    f32x16 acc;
#pragma unroll
    for (int r = 0; r < 16; ++r) acc[r] = 0.0f;

    const __fp16* ah = xh + ((size_t)g0 * 32 + ln32) * 8;
    const __fp16* al = xl + ((size_t)g0 * 32 + ln32) * 8;
    const float4* wp = (const float4*)(W + ((size_t)g0 * NV + v0 + ln32) * ND);

#pragma unroll 2
    for (int s = 0; s < KSTEPS; ++s) {
        const float4 w0 = wp[0];
        const float4 w1 = wp[1];
        wp += 2 * NV * ND / 4;
        const f16x8 a_hi = *(const f16x8*)ah;  ah += 2 * 32 * 8;
        const f16x8 a_lo = *(const f16x8*)al;  al += 2 * 32 * 8;

        const f16x2 h01 = __builtin_amdgcn_cvt_pkrtz(w0.x, w0.y);
        const f16x2 h23 = __builtin_amdgcn_cvt_pkrtz(w0.z, w0.w);
        const f16x2 h45 = __builtin_amdgcn_cvt_pkrtz(w1.x, w1.y);
        const f16x2 h67 = __builtin_amdgcn_cvt_pkrtz(w1.z, w1.w);
        const f16x8 b = {h01.x, h01.y, h23.x, h23.y, h45.x, h45.y, h67.x, h67.y};

        acc = __builtin_amdgcn_mfma_f32_32x32x16_f16(a_hi, b, acc, 0, 0, 0);
        acc = __builtin_amdgcn_mfma_f32_32x32x16_f16(a_lo, b, acc, 0, 0, 0);
    }

    // 4-wave k-reduce via LDS, then write the block's 32x32 tile as f16.
    __shared__ float red[4 * 1024];   // 16 KB
#pragma unroll
    for (int r = 0; r < 16; ++r)
        red[wave * 1024 + r * 64 + lane] = acc[r];
    __syncthreads();

#pragma unroll
    for (int j = 0; j < 4; ++j) {
        const int s  = t + j * 256;
        const float val = red[s] + red[1024 + s] + red[2048 + s] + red[3072 + s];
        const int r   = s >> 6;
        const int ln  = s & 63;
        // C/D layout (m74/m101): col = lane&31 (v), row = (reg&3)+8*(reg>>2)+4*(lane>>5) (b)
        const int row = (r & 3) + 8 * (r >> 2) + 4 * (ln >> 5);
        const int col = ln & 31;
        partial_h[((size_t)kb * NB + row) * NV + v0 + col] = (__fp16)val;
    }
}

// ---------------------------------------------------------------------------
// Kernel 3: tree reduce 8 kb-slices -> 1 (f16 in, f32 out).
// Grid: NG(16) x NB(32) = 512 blocks, 256 threads; thread t owns v-pair t.
// ---------------------------------------------------------------------------
__global__ __launch_bounds__(256) void caps_reduce8(
    const __fp16* __restrict__ partial_h, float* __restrict__ partial2)
{
    const int t = threadIdx.x;             // v-pair index (v = 2t, 2t+1)
    const int b = blockIdx.x & 31;
    const int g = blockIdx.x >> 5;         // 0..NG-1

    const __fp16* p = partial_h + ((size_t)(g * 8) * NB + b) * NV + 2 * t;
    float s0 = 0.0f, s1 = 0.0f;
#pragma unroll
    for (int j = 0; j < 8; ++j) {
        const f16x2 h = *(const f16x2*)(p + (size_t)j * NB * NV);
        s0 += (float)h.x;
        s1 += (float)h.y;
    }

    float2 o = {s0, s1};
    ((float2*)(partial2 + ((size_t)g * NB + b) * NV))[t] = o;
}

// ---------------------------------------------------------------------------
// Kernel 4: final reduce over NG groups + squash + write both outputs.
// Grid: 32 blocks (one per b) x 512 threads (one per v). Reads 1 MB.
// ---------------------------------------------------------------------------
__global__ __launch_bounds__(512) void caps_finish(
    const float* __restrict__ partial2, float* __restrict__ out)
{
    const int v = threadIdx.x;
    const int b = blockIdx.x;

    float s = 0.0f;
#pragma unroll
    for (int g = 0; g < NG; ++g)         // 16 independent coalesced loads
        s += partial2[((size_t)g * NB + b) * NV + v];

    float sq = s * s;
#pragma unroll
    for (int off = 32; off > 0; off >>= 1)
        sq += __shfl_xor(sq, off, 64);

    __shared__ float red[8];
    if ((v & 63) == 0) red[v >> 6] = sq;
    __syncthreads();
    float tot = 0.0f;
#pragma unroll
    for (int wv = 0; wv < 8; ++wv) tot += red[wv];

    // squash factor: sq/((1+sq)*sqrt(sq)) == sqrt(sq)/(1+sq)
    const float factor = sqrtf(tot) / (1.0f + tot);
    const float r = s * factor;

    out[(size_t)b * NV + v]           = r;  // output 0: t       [B,1,V]
    out[NB * NV + (size_t)b * NV + v] = r;  // output 1: outputs [B,O,V]
}

extern "C" void kernel_launch(void* const* d_in, const int* in_sizes, int n_in,
                              void* d_out, int out_size, void* d_ws, size_t ws_size,
                              hipStream_t stream) {
    const float* x = (const float*)d_in[0];   // [32, 4096, 8]
    const float* W = (const float*)d_in[1];   // [1, 4096, 512, 8]
    float* out     = (float*)d_out;           // 2 x [32,1,512] concatenated

    __fp16* xh       = (__fp16*)d_ws;                         // 2 MB
    __fp16* xl       = xh + (size_t)NB * NK;                  // 2 MB
    __fp16* partialh = xl + (size_t)NB * NK;                  // 4 MB (f16)
    float*  partial2 = (float*)(partialh + (size_t)KB * NB * NV);  // 1 MB

    x_prep<<<(NB * NK / 8) / 256, 256, 0, stream>>>(x, xh, xl);
    caps_mfma<<<KB * 16, 256, 0, stream>>>(W, xh, xl, partialh);
    caps_reduce8<<<NG * NB, 256, 0, stream>>>(partialh, partial2);
    caps_finish<<<NB, 512, 0, stream>>>(partial2, out);
}